// Round 3
// baseline (1000.927 us; speedup 1.0000x reference)
//
#include <hip/hip_runtime.h>

#define N_NODES  200000
#define N_EDGES  3200000
#define HIDDEN   64
#define N_GRAPHS 4096
#define N_CLASSES 7
#define SCAN_B   256
#define N_SCANB  ((N_NODES + SCAN_B - 1) / SCAN_B)   // 782

// ---------- degree histogram (int) ----------
__global__ void k_deg(const int* __restrict__ dst, int* __restrict__ deg) {
    int e = blockIdx.x * blockDim.x + threadIdx.x;
    if (e < N_EDGES) atomicAdd(&deg[dst[e]], 1);
}

// ---------- prefix scan pass 1: per-block exclusive scan ----------
__global__ void k_scan1(const int* __restrict__ deg, int* __restrict__ off,
                        int* __restrict__ bsum) {
    __shared__ int tmp[SCAN_B];
    int tid = threadIdx.x;
    int i = blockIdx.x * SCAN_B + tid;
    int v = (i < N_NODES) ? deg[i] : 0;
    int x = v;
    tmp[tid] = x;
    __syncthreads();
    for (int o = 1; o < SCAN_B; o <<= 1) {
        int y = (tid >= o) ? tmp[tid - o] : 0;
        __syncthreads();
        x += y;
        tmp[tid] = x;
        __syncthreads();
    }
    if (i < N_NODES) off[i] = x - v;              // exclusive within block
    if (tid == SCAN_B - 1) bsum[blockIdx.x] = x;  // block total
}

// ---------- prefix scan pass 2: parallel LDS scan of 782 block sums ----------
__global__ void k_scan2(int* __restrict__ bsum) {
    __shared__ int tmp[1024];
    int tid = threadIdx.x;
    int v = (tid < N_SCANB) ? bsum[tid] : 0;
    int x = v;
    tmp[tid] = x;
    __syncthreads();
    for (int o = 1; o < 1024; o <<= 1) {
        int y = (tid >= o) ? tmp[tid - o] : 0;
        __syncthreads();
        x += y;
        tmp[tid] = x;
        __syncthreads();
    }
    if (tid < N_SCANB) bsum[tid] = x - v;         // exclusive
}

// ---------- finalize: add block base, init cursor, compute dinv ----------
__global__ void k_fin(const int* __restrict__ deg, int* __restrict__ off,
                      const int* __restrict__ bsum, int* __restrict__ cursor,
                      float* __restrict__ dinv) {
    int i = blockIdx.x * blockDim.x + threadIdx.x;
    if (i >= N_NODES) return;
    int o = off[i] + bsum[i >> 8];
    off[i] = o;
    cursor[i] = o;
    dinv[i] = rsqrtf((float)deg[i] + 1.0f);   // +1 self loop
}

// ---------- scatter edges into CSR buckets (src only, 4B payload) ----------
__global__ void k_scatter(const int* __restrict__ src, const int* __restrict__ dst,
                          int* __restrict__ cursor, int* __restrict__ edges) {
    int e = blockIdx.x * blockDim.x + threadIdx.x;
    if (e >= N_EDGES) return;
    int s = src[e], d = dst[e];
    int pos = atomicAdd(&cursor[d], 1);
    edges[pos] = s;
}

// ---------- layer-1 pre-aggregation on raw 2-ch x ----------
__global__ void k_gather2(const int* __restrict__ edges, const int* __restrict__ off,
                          const int* __restrict__ endv, const float* __restrict__ dinv,
                          const float2* __restrict__ x2, float2* __restrict__ g2) {
    int n = blockIdx.x * blockDim.x + threadIdx.x;
    if (n >= N_NODES) return;
    float dn = dinv[n];
    float2 xv = x2[n];
    float w0 = dn * dn;
    float ax = w0 * xv.x, ay = w0 * xv.y;
    int e1 = endv[n];
    for (int j = off[n]; j < e1; ++j) {
        int s = edges[j];
        float w = dinv[s] * dn;
        float2 v = x2[s];
        ax += w * v.x; ay += w * v.y;
    }
    g2[n] = make_float2(ax, ay);
}

// ---------- layer-1 pointwise: h1 = relu(g2 @ W1 + b1) ----------
__global__ void k_mm1f(const float2* __restrict__ g2, const float* __restrict__ W1,
                       const float* __restrict__ b1, float* __restrict__ A) {
    int idx = blockIdx.x * blockDim.x + threadIdx.x;
    if (idx >= N_NODES * HIDDEN) return;
    int n = idx >> 6, c = idx & 63;
    float2 g = g2[n];
    float v = g.x * W1[c] + g.y * W1[64 + c] + b1[c];
    A[idx] = v > 0.0f ? v : 0.0f;
}

// ---------- fused layer: Aout = relu( (Â H) W + b ) ----------
// one wave per node (4 nodes / 256-thread block); aggregation via
// sub(4) x quad(16) lanes, then 64x64 matmul from LDS in the epilogue.
__global__ void k_layer(const int* __restrict__ edges, const int* __restrict__ off,
                        const int* __restrict__ endv, const float* __restrict__ dinv,
                        const float4* __restrict__ H4, const float* __restrict__ W,
                        const float* __restrict__ bias, float* __restrict__ Aout) {
    __shared__ float Ws[64 * 64];
    __shared__ float aggL[4][64];
    for (int i = threadIdx.x; i < 64 * 64; i += 256) Ws[i] = W[i];

    int ln = threadIdx.x >> 6;        // wave id within block
    int lane = threadIdx.x & 63;
    int n = blockIdx.x * 4 + ln;
    int sub = lane >> 4, q = lane & 15;
    float dn = dinv[n];
    float ax = 0.0f, ay = 0.0f, az = 0.0f, aw = 0.0f;
    if (sub == 0) {
        float w0 = dn * dn;
        float4 v = H4[n * 16 + q];
        ax = w0 * v.x; ay = w0 * v.y; az = w0 * v.z; aw = w0 * v.w;
    }
    int e1 = endv[n];
    for (int j = off[n] + sub; j < e1; j += 4) {
        int s = edges[j];
        float w = dinv[s] * dn;
        float4 v = H4[s * 16 + q];
        ax += w * v.x; ay += w * v.y; az += w * v.z; aw += w * v.w;
    }
    // reduce across the 4 sub-slots (lane bits 4,5)
    ax += __shfl_xor(ax, 16, 64); ax += __shfl_xor(ax, 32, 64);
    ay += __shfl_xor(ay, 16, 64); ay += __shfl_xor(ay, 32, 64);
    az += __shfl_xor(az, 16, 64); az += __shfl_xor(az, 32, 64);
    aw += __shfl_xor(aw, 16, 64); aw += __shfl_xor(aw, 32, 64);
    if (sub == 0) {
        aggL[ln][q * 4 + 0] = ax;
        aggL[ln][q * 4 + 1] = ay;
        aggL[ln][q * 4 + 2] = az;
        aggL[ln][q * 4 + 3] = aw;
    }
    __syncthreads();
    // matmul epilogue: thread (ln, c=lane) computes out channel c of node n
    float s = bias[lane];
#pragma unroll
    for (int k = 0; k < 64; ++k) s += aggL[ln][k] * Ws[k * 64 + lane];
    Aout[n * 64 + lane] = s > 0.0f ? s : 0.0f;
}

// ---------- segmented mean-pool accumulation (batch is sorted) ----------
#define PCHUNK 64
__global__ void k_pool(const float* __restrict__ A, const int* __restrict__ batch,
                       float* __restrict__ sums, float* __restrict__ cnts) {
    int c = threadIdx.x;            // 64 threads = 64 channels
    int n0 = blockIdx.x * PCHUNK;
    int n1 = n0 + PCHUNK; if (n1 > N_NODES) n1 = N_NODES;
    int gcur = batch[n0];
    float acc = 0.0f;
    int cnt = 0;
    for (int n = n0; n < n1; ++n) {
        int g = batch[n];
        if (g != gcur) {
            atomicAdd(&sums[gcur * 64 + c], acc);
            if (c == 0) atomicAdd(&cnts[gcur], (float)cnt);
            acc = 0.0f; cnt = 0; gcur = g;
        }
        acc += A[n * 64 + c];
        ++cnt;
    }
    atomicAdd(&sums[gcur * 64 + c], acc);
    if (c == 0) atomicAdd(&cnts[gcur], (float)cnt);
}

// ---------- MLP head ----------
__global__ void k_head(const float* __restrict__ sums, const float* __restrict__ cnts,
                       const float* __restrict__ Wf1, const float* __restrict__ bf1,
                       const float* __restrict__ Wf2, const float* __restrict__ bf2,
                       float* __restrict__ out) {
    __shared__ float p[64];
    __shared__ float h[64];
    int g = blockIdx.x;
    int c = threadIdx.x;
    float cnt = cnts[g];
    cnt = cnt > 1.0f ? cnt : 1.0f;
    p[c] = sums[g * 64 + c] / cnt;
    __syncthreads();
    float s = bf1[c];
#pragma unroll
    for (int k = 0; k < 64; ++k) s += p[k] * Wf1[k * 64 + c];
    h[c] = s > 0.0f ? s : 0.0f;
    __syncthreads();
    if (c < N_CLASSES) {
        float o = bf2[c];
#pragma unroll
        for (int k = 0; k < 64; ++k) o += h[k] * Wf2[k * N_CLASSES + c];
        out[g * N_CLASSES + c] = o;
    }
}

extern "C" void kernel_launch(void* const* d_in, const int* in_sizes, int n_in,
                              void* d_out, int out_size, void* d_ws, size_t ws_size,
                              hipStream_t stream) {
    const float* x   = (const float*)d_in[0];
    const int*   ei  = (const int*)d_in[1];
    const int*   bat = (const int*)d_in[2];
    const float* W1  = (const float*)d_in[3];
    const float* b1  = (const float*)d_in[4];
    const float* W2  = (const float*)d_in[5];
    const float* b2  = (const float*)d_in[6];
    const float* W3  = (const float*)d_in[7];
    const float* b3  = (const float*)d_in[8];
    const float* Wf1 = (const float*)d_in[9];
    const float* bf1 = (const float*)d_in[10];
    const float* Wf2 = (const float*)d_in[11];
    const float* bf2 = (const float*)d_in[12];
    float* out = (float*)d_out;

    const int* src = ei;
    const int* dst = ei + N_EDGES;

    char* p = (char*)d_ws;
    float* A    = (float*)p;                    p += (size_t)N_NODES * 64 * 4;
    float* B    = (float*)p;                    p += (size_t)N_NODES * 64 * 4;
    int*   edges= (int*)p;                      p += (size_t)N_EDGES * 4;
    int*   deg  = (int*)p;                      p += (size_t)N_NODES * 4;
    int*   off  = (int*)p;                      p += (size_t)N_NODES * 4;
    int*   cur  = (int*)p;                      p += (size_t)N_NODES * 4;
    float* dinv = (float*)p;                    p += (size_t)N_NODES * 4;
    float* g2   = (float*)p;                    p += (size_t)N_NODES * 2 * 4;
    int*   bsum = (int*)p;                      p += (size_t)1024 * 4;
    float* sums = (float*)p;                    p += (size_t)N_GRAPHS * 64 * 4;
    float* cnts = (float*)p;                    p += (size_t)N_GRAPHS * 4;

    hipMemsetAsync(deg, 0, (size_t)N_NODES * 4, stream);
    hipMemsetAsync(sums, 0, (size_t)(N_GRAPHS * 64 + N_GRAPHS) * 4, stream);

    const int BT = 256;
    int gEdges = (N_EDGES + BT - 1) / BT;
    int gNodes = (N_NODES + BT - 1) / BT;
    int gNH    = (N_NODES * HIDDEN + BT - 1) / BT;
    int gWave  = N_NODES / 4;                   // 50000, exact

    // ---- CSR build ----
    k_deg<<<gEdges, BT, 0, stream>>>(dst, deg);
    k_scan1<<<N_SCANB, SCAN_B, 0, stream>>>(deg, off, bsum);
    k_scan2<<<1, 1024, 0, stream>>>(bsum);
    k_fin<<<gNodes, BT, 0, stream>>>(deg, off, bsum, cur, dinv);
    k_scatter<<<gEdges, BT, 0, stream>>>(src, dst, cur, edges);

    // ---- layer 1: aggregate raw x (2ch), then W1+bias+relu ----
    k_gather2<<<gNodes, BT, 0, stream>>>(edges, off, cur, dinv, (const float2*)x, (float2*)g2);
    k_mm1f<<<gNH, BT, 0, stream>>>((const float2*)g2, W1, b1, A);

    // ---- layer 2 (fused aggregate + matmul + bias + relu) ----
    k_layer<<<gWave, BT, 0, stream>>>(edges, off, cur, dinv, (const float4*)A, W2, b2, B);

    // ---- layer 3 ----
    k_layer<<<gWave, BT, 0, stream>>>(edges, off, cur, dinv, (const float4*)B, W3, b3, A);

    // ---- pool + head ----
    k_pool<<<(N_NODES + PCHUNK - 1) / PCHUNK, 64, 0, stream>>>(A, bat, sums, cnts);
    k_head<<<N_GRAPHS, 64, 0, stream>>>(sums, cnts, Wf1, bf1, Wf2, bf2, out);
}

// Round 4
// 632.027 us; speedup vs baseline: 1.5837x; 1.5837x over previous
//
#include <hip/hip_runtime.h>

#define N_NODES  200000
#define N_EDGES  3200000
#define HIDDEN   64
#define N_GRAPHS 4096
#define N_CLASSES 7
#define NBUCK    196          // ceil(N_NODES / 1024)
#define BSHIFT   10
#define BMASK    1023

// ---------- coarse histogram (196 buckets) ----------
#define CH_EPT 16
__global__ void k_chist(const int* __restrict__ dst, int* __restrict__ chist) {
    __shared__ int h[NBUCK];
    for (int i = threadIdx.x; i < NBUCK; i += 256) h[i] = 0;
    __syncthreads();
    int base = blockIdx.x * 256 * CH_EPT + threadIdx.x;
    for (int k = 0; k < CH_EPT; ++k) {
        int e = base + k * 256;
        if (e < N_EDGES) atomicAdd(&h[dst[e] >> BSHIFT], 1);
    }
    __syncthreads();
    for (int i = threadIdx.x; i < NBUCK; i += 256) atomicAdd(&chist[i], h[i]);
}

// ---------- scan of 196 bucket counts ----------
__global__ void k_cscan(const int* __restrict__ chist, int* __restrict__ cbase,
                        int* __restrict__ gcur) {
    __shared__ int tmp[256];
    int tid = threadIdx.x;
    int v = (tid < NBUCK) ? chist[tid] : 0;
    int x = v; tmp[tid] = x; __syncthreads();
    for (int o = 1; o < 256; o <<= 1) {
        int y = (tid >= o) ? tmp[tid - o] : 0;
        __syncthreads();
        x += y; tmp[tid] = x;
        __syncthreads();
    }
    if (tid < NBUCK) { cbase[tid] = x - v; gcur[tid] = x - v; }
    if (tid == 0) cbase[NBUCK] = N_EDGES;
}

// ---------- coarse partition: stage[pos] = (src<<10)|(dst&1023) ----------
#define PT_EPT 32
__global__ void k_part(const int* __restrict__ src, const int* __restrict__ dst,
                       int* __restrict__ gcur, int* __restrict__ stage) {
    __shared__ int lh[NBUCK];
    __shared__ int lbase[NBUCK];
    __shared__ int lcur[NBUCK];
    for (int i = threadIdx.x; i < NBUCK; i += 256) { lh[i] = 0; lcur[i] = 0; }
    __syncthreads();
    int base = blockIdx.x * 256 * PT_EPT + threadIdx.x;
    for (int k = 0; k < PT_EPT; ++k) {
        int e = base + k * 256;
        if (e < N_EDGES) atomicAdd(&lh[dst[e] >> BSHIFT], 1);
    }
    __syncthreads();
    for (int i = threadIdx.x; i < NBUCK; i += 256)
        if (lh[i] > 0) lbase[i] = atomicAdd(&gcur[i], lh[i]);
    __syncthreads();
    for (int k = 0; k < PT_EPT; ++k) {
        int e = base + k * 256;
        if (e < N_EDGES) {
            int d = dst[e], b = d >> BSHIFT;
            int lp = atomicAdd(&lcur[b], 1);
            stage[lbase[b] + lp] = (src[e] << BSHIFT) | (d & BMASK);
        }
    }
}

// ---------- per-bucket exact sort + CSR metadata (off/endv/dinv) ----------
__global__ void k_sort(const int* __restrict__ stage, const int* __restrict__ cbase,
                       int* __restrict__ edges, int* __restrict__ off,
                       int* __restrict__ endv, float* __restrict__ dinv) {
    __shared__ int hist[1024];
    __shared__ int tmp[256];
    int b = blockIdx.x, tid = threadIdx.x;
    int cb0 = cbase[b], cb1 = cbase[b + 1];
    for (int k = 0; k < 4; ++k) hist[tid * 4 + k] = 0;
    __syncthreads();
    for (int j = cb0 + tid; j < cb1; j += 256)
        atomicAdd(&hist[stage[j] & BMASK], 1);
    __syncthreads();
    int c0 = hist[tid*4], c1 = hist[tid*4+1], c2 = hist[tid*4+2], c3 = hist[tid*4+3];
    int s = c0 + c1 + c2 + c3;
    int x = s; tmp[tid] = x; __syncthreads();
    for (int o = 1; o < 256; o <<= 1) {
        int y = (tid >= o) ? tmp[tid - o] : 0;
        __syncthreads();
        x += y; tmp[tid] = x;
        __syncthreads();
    }
    int run = x - s;                 // exclusive prefix of this thread's 4 counters
    int nbase = b << BSHIFT;
    int counts[4] = {c0, c1, c2, c3};
    for (int k = 0; k < 4; ++k) {
        int v = tid * 4 + k;
        hist[v] = run;               // local cursor start
        int node = nbase + v;
        if (node < N_NODES) {
            off[node]  = cb0 + run;
            endv[node] = cb0 + run + counts[k];
            dinv[node] = rsqrtf((float)counts[k] + 1.0f);   // +1 self loop
        }
        run += counts[k];
    }
    __syncthreads();
    for (int j = cb0 + tid; j < cb1; j += 256) {
        int p = stage[j];
        int pos = atomicAdd(&hist[p & BMASK], 1);
        edges[cb0 + pos] = p >> BSHIFT;     // src
    }
}

// ---------- layer-1 pre-aggregation on raw 2-ch x ----------
__global__ void k_gather2(const int* __restrict__ edges, const int* __restrict__ off,
                          const int* __restrict__ endv, const float* __restrict__ dinv,
                          const float2* __restrict__ x2, float2* __restrict__ g2) {
    int n = blockIdx.x * blockDim.x + threadIdx.x;
    if (n >= N_NODES) return;
    float dn = dinv[n];
    float2 xv = x2[n];
    float w0 = dn * dn;
    float ax = w0 * xv.x, ay = w0 * xv.y;
    int e1 = endv[n];
    for (int j = off[n]; j < e1; ++j) {
        int s = edges[j];
        float w = dinv[s] * dn;
        float2 v = x2[s];
        ax += w * v.x; ay += w * v.y;
    }
    g2[n] = make_float2(ax, ay);
}

// ---------- layer-1 pointwise: h1 = relu(g2 @ W1 + b1) ----------
__global__ void k_mm1f(const float2* __restrict__ g2, const float* __restrict__ W1,
                       const float* __restrict__ b1, float* __restrict__ A) {
    int idx = blockIdx.x * blockDim.x + threadIdx.x;
    if (idx >= N_NODES * HIDDEN) return;
    int n = idx >> 6, c = idx & 63;
    float2 g = g2[n];
    float v = g.x * W1[c] + g.y * W1[64 + c] + b1[c];
    A[idx] = v > 0.0f ? v : 0.0f;
}

// ---------- fused layer: Aout = relu( (Â H) W + b ), 16 nodes/block ----------
#define NPB 16
__global__ void k_layer(const int* __restrict__ edges, const int* __restrict__ off,
                        const int* __restrict__ endv, const float* __restrict__ dinv,
                        const float4* __restrict__ H4, const float* __restrict__ W,
                        const float* __restrict__ bias, float* __restrict__ Aout) {
    __shared__ float Ws[64 * 64];
    __shared__ float aggL[4][64];
    for (int i = threadIdx.x; i < 64 * 64; i += 256) Ws[i] = W[i];
    int ln = threadIdx.x >> 6, lane = threadIdx.x & 63;
    int sub = lane >> 4, q = lane & 15;
    for (int it = 0; it < NPB / 4; ++it) {
        int n = blockIdx.x * NPB + it * 4 + ln;
        float dn = dinv[n];
        float ax = 0.0f, ay = 0.0f, az = 0.0f, aw = 0.0f;
        if (sub == 0) {
            float w0 = dn * dn;
            float4 v = H4[n * 16 + q];
            ax = w0 * v.x; ay = w0 * v.y; az = w0 * v.z; aw = w0 * v.w;
        }
        int e1 = endv[n];
        for (int j = off[n] + sub; j < e1; j += 4) {
            int s = edges[j];
            float w = dinv[s] * dn;
            float4 v = H4[s * 16 + q];
            ax += w * v.x; ay += w * v.y; az += w * v.z; aw += w * v.w;
        }
        ax += __shfl_xor(ax, 16, 64); ax += __shfl_xor(ax, 32, 64);
        ay += __shfl_xor(ay, 16, 64); ay += __shfl_xor(ay, 32, 64);
        az += __shfl_xor(az, 16, 64); az += __shfl_xor(az, 32, 64);
        aw += __shfl_xor(aw, 16, 64); aw += __shfl_xor(aw, 32, 64);
        __syncthreads();            // aggL free (prev iter's readers done) + Ws ready
        if (sub == 0) {
            aggL[ln][q * 4 + 0] = ax;
            aggL[ln][q * 4 + 1] = ay;
            aggL[ln][q * 4 + 2] = az;
            aggL[ln][q * 4 + 3] = aw;
        }
        __syncthreads();
        float sacc = bias[lane];
#pragma unroll
        for (int k = 0; k < 64; ++k) sacc += aggL[ln][k] * Ws[k * 64 + lane];
        Aout[n * 64 + lane] = sacc > 0.0f ? sacc : 0.0f;
    }
}

// ---------- segmented mean-pool accumulation (batch is sorted) ----------
#define PCHUNK 64
__global__ void k_pool(const float* __restrict__ A, const int* __restrict__ batch,
                       float* __restrict__ sums, float* __restrict__ cnts) {
    int c = threadIdx.x;
    int n0 = blockIdx.x * PCHUNK;
    int n1 = n0 + PCHUNK; if (n1 > N_NODES) n1 = N_NODES;
    int gcur = batch[n0];
    float acc = 0.0f;
    int cnt = 0;
    for (int n = n0; n < n1; ++n) {
        int g = batch[n];
        if (g != gcur) {
            atomicAdd(&sums[gcur * 64 + c], acc);
            if (c == 0) atomicAdd(&cnts[gcur], (float)cnt);
            acc = 0.0f; cnt = 0; gcur = g;
        }
        acc += A[n * 64 + c];
        ++cnt;
    }
    atomicAdd(&sums[gcur * 64 + c], acc);
    if (c == 0) atomicAdd(&cnts[gcur], (float)cnt);
}

// ---------- MLP head ----------
__global__ void k_head(const float* __restrict__ sums, const float* __restrict__ cnts,
                       const float* __restrict__ Wf1, const float* __restrict__ bf1,
                       const float* __restrict__ Wf2, const float* __restrict__ bf2,
                       float* __restrict__ out) {
    __shared__ float p[64];
    __shared__ float h[64];
    int g = blockIdx.x;
    int c = threadIdx.x;
    float cnt = cnts[g];
    cnt = cnt > 1.0f ? cnt : 1.0f;
    p[c] = sums[g * 64 + c] / cnt;
    __syncthreads();
    float s = bf1[c];
#pragma unroll
    for (int k = 0; k < 64; ++k) s += p[k] * Wf1[k * 64 + c];
    h[c] = s > 0.0f ? s : 0.0f;
    __syncthreads();
    if (c < N_CLASSES) {
        float o = bf2[c];
#pragma unroll
        for (int k = 0; k < 64; ++k) o += h[k] * Wf2[k * N_CLASSES + c];
        out[g * N_CLASSES + c] = o;
    }
}

extern "C" void kernel_launch(void* const* d_in, const int* in_sizes, int n_in,
                              void* d_out, int out_size, void* d_ws, size_t ws_size,
                              hipStream_t stream) {
    const float* x   = (const float*)d_in[0];
    const int*   ei  = (const int*)d_in[1];
    const int*   bat = (const int*)d_in[2];
    const float* W1  = (const float*)d_in[3];
    const float* b1  = (const float*)d_in[4];
    const float* W2  = (const float*)d_in[5];
    const float* b2  = (const float*)d_in[6];
    const float* W3  = (const float*)d_in[7];
    const float* b3  = (const float*)d_in[8];
    const float* Wf1 = (const float*)d_in[9];
    const float* bf1 = (const float*)d_in[10];
    const float* Wf2 = (const float*)d_in[11];
    const float* bf2 = (const float*)d_in[12];
    float* out = (float*)d_out;

    const int* src = ei;
    const int* dst = ei + N_EDGES;

    char* p = (char*)d_ws;
    float* A     = (float*)p;   p += (size_t)N_NODES * 64 * 4;
    float* B     = (float*)p;   p += (size_t)N_NODES * 64 * 4;
    int*   stage = (int*)p;     p += (size_t)N_EDGES * 4;
    int*   edges = (int*)p;     p += (size_t)N_EDGES * 4;
    int*   off   = (int*)p;     p += (size_t)N_NODES * 4;
    int*   endv  = (int*)p;     p += (size_t)N_NODES * 4;
    float* dinv  = (float*)p;   p += (size_t)N_NODES * 4;
    float* g2    = (float*)p;   p += (size_t)N_NODES * 2 * 4;
    int*   chist = (int*)p;     p += (size_t)256 * 4;
    int*   cbase = (int*)p;     p += (size_t)256 * 4;
    int*   gcur  = (int*)p;     p += (size_t)256 * 4;
    float* sums  = (float*)p;   p += (size_t)N_GRAPHS * 64 * 4;
    float* cnts  = (float*)p;   p += (size_t)N_GRAPHS * 4;

    hipMemsetAsync(chist, 0, 256 * 4, stream);
    hipMemsetAsync(sums, 0, (size_t)(N_GRAPHS * 64 + N_GRAPHS) * 4, stream);

    const int BT = 256;
    int gNodes = (N_NODES + BT - 1) / BT;
    int gNH    = (N_NODES * HIDDEN + BT - 1) / BT;
    int gChist = (N_EDGES + 256 * CH_EPT - 1) / (256 * CH_EPT);   // 782
    int gPart  = (N_EDGES + 256 * PT_EPT - 1) / (256 * PT_EPT);   // 391
    int gLayer = N_NODES / NPB;                                   // 12500

    // ---- CSR build (binned, no global scatter over full buffer) ----
    k_chist<<<gChist, BT, 0, stream>>>(dst, chist);
    k_cscan<<<1, 256, 0, stream>>>(chist, cbase, gcur);
    k_part<<<gPart, BT, 0, stream>>>(src, dst, gcur, stage);
    k_sort<<<NBUCK, 256, 0, stream>>>(stage, cbase, edges, off, endv, dinv);

    // ---- layer 1: aggregate raw x (2ch), then W1+bias+relu ----
    k_gather2<<<gNodes, BT, 0, stream>>>(edges, off, endv, dinv, (const float2*)x, (float2*)g2);
    k_mm1f<<<gNH, BT, 0, stream>>>((const float2*)g2, W1, b1, A);

    // ---- layers 2,3 (fused aggregate + matmul + bias + relu) ----
    k_layer<<<gLayer, BT, 0, stream>>>(edges, off, endv, dinv, (const float4*)A, W2, b2, B);
    k_layer<<<gLayer, BT, 0, stream>>>(edges, off, endv, dinv, (const float4*)B, W3, b3, A);

    // ---- pool + head ----
    k_pool<<<(N_NODES + PCHUNK - 1) / PCHUNK, 64, 0, stream>>>(A, bat, sums, cnts);
    k_head<<<N_GRAPHS, 64, 0, stream>>>(sums, cnts, Wf1, bf1, Wf2, bf2, out);
}